// Round 9
// baseline (1158.862 us; speedup 1.0000x reference)
//
#include <hip/hip_runtime.h>
#include <hip/hip_bf16.h>

#define VOCAB 50257
#define NB    2048
#define NE    128
#define NCH   393                 // ceil(VOCAB/128); LSE tiles = NCH*16 = 6288
#define NLSE  (NCH * 16)
#define OCH   99                  // ceil(VOCAB/512); OUT tiles = OCH*64 = 6336
#define ONT   (OCH * 64)
#define NTR   786                 // transpose tiles (64 vocab cols each)
#define GRID  512

typedef __bf16 bf16x8 __attribute__((ext_vector_type(8)));
typedef float  f32x4  __attribute__((ext_vector_type(4)));

// Deadlock-safe manual grid barrier: requires all GRID blocks co-resident,
// guaranteed by __launch_bounds__(256,2) (>=2 blocks/CU, 512 <= 2*256).
// Counters zeroed by hipMemsetAsync before each launch; each used once.
__device__ __forceinline__ void gridbar(unsigned* bar, int which) {
  __syncthreads();
  if (threadIdx.x == 0) {
    __threadfence();
    __hip_atomic_fetch_add(&bar[which * 16], 1u, __ATOMIC_ACQ_REL, __HIP_MEMORY_SCOPE_AGENT);
    while (__hip_atomic_load(&bar[which * 16], __ATOMIC_ACQUIRE, __HIP_MEMORY_SCOPE_AGENT) < (unsigned)GRID)
      __builtin_amdgcn_s_sleep(2);
    __threadfence();
  }
  __syncthreads();
}

__global__ __launch_bounds__(256, 2) void k_mega(
    const float* __restrict__ oh, const float* __restrict__ w1,
    const float* __restrict__ w2, float* __restrict__ out,
    __hip_bfloat16* __restrict__ z1, __hip_bfloat16* __restrict__ w2T,
    float* __restrict__ pmax, float* __restrict__ psum, float* __restrict__ lse,
    unsigned* __restrict__ bar) {
  __shared__ __hip_bfloat16 tile[64][130];
  __shared__ float sm[2][128];
  __shared__ float ss[2][128];

  const int bid  = blockIdx.x;
  const int tid  = threadIdx.x;
  const int lane = tid & 63;
  const int wave = tid >> 6;

  // ============ Phase A: find+gather (wave per row, 512*4 = 2048) ∥ transpose ============
  {
    const int w = bid * 4 + wave;
    const float* row = oh + (long)w * VOCAB;
    const int a = (4 - (w & 3)) & 3;
    const f32x4* rp = reinterpret_cast<const f32x4*>(row + a);

    int pos = -1;
    f32x4 v[4], nv[4];
#pragma unroll
    for (int j = 0; j < 4; ++j) v[j] = rp[j * 64 + lane];
    bool found = false;
    for (int i = 0; i < 48 && !found; ++i) {
      if (i + 1 < 48) {
#pragma unroll
        for (int j = 0; j < 4; ++j) nv[j] = rp[(i + 1) * 256 + j * 64 + lane];
      }
      bool f = false;
#pragma unroll
      for (int j = 0; j < 4; ++j)
        f |= (v[j][0] != 0.f) | (v[j][1] != 0.f) | (v[j][2] != 0.f) | (v[j][3] != 0.f);
      if (f) {
#pragma unroll
        for (int j = 0; j < 4; ++j)
#pragma unroll
          for (int k = 0; k < 4; ++k)
            if (v[j][k] != 0.f) pos = a + (i * 256 + j * 64 + lane) * 4 + k;
      }
      found = __any(f);
      if (!found) {
#pragma unroll
        for (int j = 0; j < 4; ++j) v[j] = nv[j];
      }
    }
    if (!found) {
      if (lane < a && row[lane] != 0.f) pos = lane;
      for (int e = a + 49152 + lane; e < VOCAB; e += 64)
        if (row[e] != 0.f) pos = e;
    }
#pragma unroll
    for (int off = 1; off < 64; off <<= 1) {
      int o = __shfl_xor(pos, off);
      pos = pos > o ? pos : o;
    }
    if (pos >= 0) {
      float2 wv = *reinterpret_cast<const float2*>(w1 + (long)pos * NE + lane * 2);
      ushort2 p;
      p.x = (ushort)__bfloat16_as_ushort(__float2bfloat16(wv.x));
      p.y = (ushort)__bfloat16_as_ushort(__float2bfloat16(wv.y));
      *reinterpret_cast<ushort2*>(z1 + (long)w * NE + lane * 2) = p;
    }
    // transpose tiles, grid-stride
    for (int u = bid; u < NTR; u += GRID) {
      const int v0 = u * 64;
      const int tv = tid & 63;
      const int te = tid >> 6;
      const int vv0 = v0 + tv;
      __syncthreads();
#pragma unroll
      for (int e0 = 0; e0 < NE; e0 += 4) {
        int e = e0 + te;
        float val = (vv0 < VOCAB) ? w2[(long)e * VOCAB + vv0] : 0.f;
        tile[tv][e] = __float2bfloat16(val);
      }
      __syncthreads();
#pragma unroll
      for (int it = 0; it < 16; ++it) {
        int f  = it * 256 + tid;
        int r  = f >> 6;
        int c2 = f & 63;
        int vv = v0 + r;
        if (vv < VOCAB) {
          ushort2 p;
          p.x = *reinterpret_cast<const unsigned short*>(&tile[r][2 * c2]);
          p.y = *reinterpret_cast<const unsigned short*>(&tile[r][2 * c2 + 1]);
          reinterpret_cast<ushort2*>(w2T + (long)vv * NE)[c2] = p;
        }
      }
    }
  }
  gridbar(bar, 0);

  // ============ Phase B: LSE GEMM partials (128x128 tiles) ============
  {
    const int wm = wave >> 1, wn = wave & 1;
    const int l15 = lane & 15, lhi = lane >> 4;
    for (int t = bid; t < NLSE; t += GRID) {
      const int chunk = t >> 4;
      const int rowg  = t & 15;
      const int row0 = rowg * 128 + wm * 64;
      const int col0 = chunk * 128 + wn * 64;

      bf16x8 bz[4][4];
      const __hip_bfloat16* zp = z1 + (row0 + l15) * NE + lhi * 8;
#pragma unroll
      for (int ri = 0; ri < 4; ++ri)
#pragma unroll
        for (int kb = 0; kb < 4; ++kb)
          bz[ri][kb] = *reinterpret_cast<const bf16x8*>(zp + ri * 16 * NE + kb * 32);

      f32x4 acc[4][4];
#pragma unroll
      for (int vi = 0; vi < 4; ++vi)
#pragma unroll
        for (int ri = 0; ri < 4; ++ri)
          acc[vi][ri] = (f32x4){0.f, 0.f, 0.f, 0.f};

#pragma unroll
      for (int vi = 0; vi < 4; ++vi) {
        int col  = col0 + vi * 16 + l15;
        int colc = col < VOCAB ? col : VOCAB - 1;
        const __hip_bfloat16* wp = w2T + colc * NE + lhi * 8;
        bf16x8 aw[4];
#pragma unroll
        for (int kb = 0; kb < 4; ++kb)
          aw[kb] = *reinterpret_cast<const bf16x8*>(wp + kb * 32);
#pragma unroll
        for (int ri = 0; ri < 4; ++ri)
#pragma unroll
          for (int kb = 0; kb < 4; ++kb)
            acc[vi][ri] = __builtin_amdgcn_mfma_f32_16x16x32_bf16(aw[kb], bz[ri][kb], acc[vi][ri], 0, 0, 0);
      }

#pragma unroll
      for (int ri = 0; ri < 4; ++ri) {
        float v[16];
        float m = -INFINITY;
#pragma unroll
        for (int vi = 0; vi < 4; ++vi)
#pragma unroll
          for (int r = 0; r < 4; ++r) {
            int col = col0 + vi * 16 + lhi * 4 + r;
            float x = (col < VOCAB) ? acc[vi][ri][r] : -INFINITY;
            v[vi * 4 + r] = x;
            m = fmaxf(m, x);
          }
        m = fmaxf(m, __shfl_xor(m, 16));
        m = fmaxf(m, __shfl_xor(m, 32));
        float s = 0.f;
#pragma unroll
        for (int tt = 0; tt < 16; ++tt) s += __expf(v[tt] - m);
        s += __shfl_xor(s, 16);
        s += __shfl_xor(s, 32);
        if (lhi == 0) {
          int lr = wm * 64 + ri * 16 + l15;
          sm[wn][lr] = m;
          ss[wn][lr] = s;
        }
      }
      __syncthreads();
      if (tid < 128) {
        int r = tid;
        float m0 = sm[0][r], m1 = sm[1][r];
        float s0 = ss[0][r], s1 = ss[1][r];
        float M = fmaxf(m0, m1);
        float S = s0 * __expf(m0 - M) + s1 * __expf(m1 - M);
        int o = chunk * NB + rowg * 128 + r;
        pmax[o] = M;
        psum[o] = S;
      }
      __syncthreads();
    }
  }
  gridbar(bar, 1);

  // ============ Phase C: merge partials -> lse (blocks 0..7) ============
  if (bid < 8) {
    int b = bid * 256 + tid;
    float M = -INFINITY;
#pragma unroll 8
    for (int c = 0; c < NCH; ++c) M = fmaxf(M, pmax[c * NB + b]);
    float S = 0.f;
#pragma unroll 8
    for (int c = 0; c < NCH; ++c) S += psum[c * NB + b] * __expf(pmax[c * NB + b] - M);
    lse[b] = M + __logf(S);
  }
  gridbar(bar, 2);

  // ============ Phase D: OUT (32-row x 512-col tiles, direct stores) ============
  {
    const int l15 = lane & 15, lhi = lane >> 4;
    for (int t = bid; t < ONT; t += GRID) {
      const int chunk = t >> 6;
      const int rowg  = t & 63;
      const int row0 = rowg * 32;
      const int col0 = chunk * 512 + wave * 128;

      bf16x8 bz[2][4];
      const __hip_bfloat16* zp = z1 + (row0 + l15) * NE + lhi * 8;
#pragma unroll
      for (int ri = 0; ri < 2; ++ri)
#pragma unroll
        for (int kb = 0; kb < 4; ++kb)
          bz[ri][kb] = *reinterpret_cast<const bf16x8*>(zp + ri * 16 * NE + kb * 32);

      f32x4 acc[8][2];
#pragma unroll
      for (int vi = 0; vi < 8; ++vi)
#pragma unroll
        for (int ri = 0; ri < 2; ++ri)
          acc[vi][ri] = (f32x4){0.f, 0.f, 0.f, 0.f};

#pragma unroll
      for (int vi = 0; vi < 8; ++vi) {
        int col  = col0 + vi * 16 + l15;
        int colc = col < VOCAB ? col : VOCAB - 1;
        const __hip_bfloat16* wp = w2T + colc * NE + lhi * 8;
        bf16x8 aw[4];
#pragma unroll
        for (int kb = 0; kb < 4; ++kb)
          aw[kb] = *reinterpret_cast<const bf16x8*>(wp + kb * 32);
#pragma unroll
        for (int ri = 0; ri < 2; ++ri)
#pragma unroll
          for (int kb = 0; kb < 4; ++kb)
            acc[vi][ri] = __builtin_amdgcn_mfma_f32_16x16x32_bf16(aw[kb], bz[ri][kb], acc[vi][ri], 0, 0, 0);
      }

      float lsev[2] = {lse[row0 + l15], lse[row0 + 16 + l15]};
#pragma unroll
      for (int ri = 0; ri < 2; ++ri) {
        long obase = (long)(row0 + ri * 16 + l15) * VOCAB;
#pragma unroll
        for (int vi = 0; vi < 8; ++vi) {
          int col = col0 + vi * 16 + lhi * 4;
          f32x4 v = acc[vi][ri] - lsev[ri];
          if (col + 3 < VOCAB) {
            *reinterpret_cast<f32x4*>(out + obase + col) = v;
          } else {
#pragma unroll
            for (int r = 0; r < 4; ++r)
              if (col + r < VOCAB) out[obase + col + r] = v[r];
          }
        }
      }
    }
  }
}

extern "C" void kernel_launch(void* const* d_in, const int* in_sizes, int n_in,
                              void* d_out, int out_size, void* d_ws, size_t ws_size,
                              hipStream_t stream) {
  const float* one_hot = (const float*)d_in[0];
  const float* w1      = (const float*)d_in[1];
  const float* w2      = (const float*)d_in[2];
  float* out = (float*)d_out;

  char* ws = (char*)d_ws;
  unsigned*       bar  = (unsigned*)ws;                  // 256 B barrier counters
  __hip_bfloat16* z1   = (__hip_bfloat16*)(ws + 8192);   // 512 KB
  __hip_bfloat16* w2T  = (__hip_bfloat16*)(ws + 532480); // 12.87 MB
  float*          pmax = (float*)(ws + 13398272);        // 3.22 MB
  float*          psum = (float*)(ws + 16617728);        // 3.22 MB
  float*          lse  = (float*)(ws + 19968256);        // 8 KB

  hipMemsetAsync(bar, 0, 256, stream);
  k_mega<<<GRID, 256, 0, stream>>>(one_hot, w1, w2, out, z1, w2T, pmax, psum, lse, bar);
}

// Round 10
// 981.654 us; speedup vs baseline: 1.1805x; 1.1805x over previous
//
#include <hip/hip_runtime.h>
#include <hip/hip_bf16.h>

#define VOCAB 50257
#define NB    2048
#define NE    128
#define NCH   393              // ceil(VOCAB/128)  (LSE pass chunking)
#define NWG   (NCH * (NB/128)) // 6288 = 8 * 786
#define NFIND (NB / 4)         // 512 find blocks
#define NTR   ((VOCAB + 63) / 64) // 786 transpose blocks
#define OCH   99               // ceil(VOCAB/512)  (OUT pass chunking)
#define ORG   (NB / 32)        // 64 row groups
#define ONWG  (OCH * ORG)      // 6336 = 8 * 792

typedef __bf16 bf16x8 __attribute__((ext_vector_type(8)));
typedef float  f32x4  __attribute__((ext_vector_type(4)));

// ---------------- fused prep: find+gather | transpose.  REP-instrumented (idempotent). ----------------
__global__ __launch_bounds__(256) void k_prep(const float* __restrict__ oh,
                                              const float* __restrict__ w1,
                                              const float* __restrict__ w2,
                                              __hip_bfloat16* __restrict__ z1,
                                              __hip_bfloat16* __restrict__ w2T,
                                              int reps) {
  __shared__ __hip_bfloat16 tile[64][130];
  for (int rep = 0; rep < reps; ++rep) {
    asm volatile("" ::: "memory");   // defeat cross-rep load hoisting
    if (blockIdx.x < NFIND) {
      const int w    = (blockIdx.x * 256 + threadIdx.x) >> 6;
      const int lane = threadIdx.x & 63;
      const float* row = oh + (long)w * VOCAB;
      const int a = (4 - (w & 3)) & 3;
      const f32x4* rp = reinterpret_cast<const f32x4*>(row + a);

      int pos = -1;
      f32x4 v[4], nv[4];
#pragma unroll
      for (int j = 0; j < 4; ++j) v[j] = rp[j * 64 + lane];
      bool found = false;
      for (int i = 0; i < 48 && !found; ++i) {
        if (i + 1 < 48) {
#pragma unroll
          for (int j = 0; j < 4; ++j) nv[j] = rp[(i + 1) * 256 + j * 64 + lane];
        }
        bool f = false;
#pragma unroll
        for (int j = 0; j < 4; ++j)
          f |= (v[j][0] != 0.f) | (v[j][1] != 0.f) | (v[j][2] != 0.f) | (v[j][3] != 0.f);
        if (f) {
#pragma unroll
          for (int j = 0; j < 4; ++j)
#pragma unroll
            for (int k = 0; k < 4; ++k)
              if (v[j][k] != 0.f) pos = a + (i * 256 + j * 64 + lane) * 4 + k;
        }
        found = __any(f);
        if (!found) {
#pragma unroll
          for (int j = 0; j < 4; ++j) v[j] = nv[j];
        }
      }
      if (!found) {
        if (lane < a && row[lane] != 0.f) pos = lane;
        for (int e = a + 49152 + lane; e < VOCAB; e += 64)
          if (row[e] != 0.f) pos = e;
      }
#pragma unroll
      for (int off = 1; off < 64; off <<= 1) {
        int o = __shfl_xor(pos, off);
        pos = pos > o ? pos : o;
      }
      if (pos >= 0) {
        float2 wv = *reinterpret_cast<const float2*>(w1 + (long)pos * NE + lane * 2);
        ushort2 p;
        p.x = (ushort)__bfloat16_as_ushort(__float2bfloat16(wv.x));
        p.y = (ushort)__bfloat16_as_ushort(__float2bfloat16(wv.y));
        *reinterpret_cast<ushort2*>(z1 + (long)w * NE + lane * 2) = p;
      }
    } else {
      const int v0 = (blockIdx.x - NFIND) * 64;
      const int tv = threadIdx.x & 63;
      const int te = threadIdx.x >> 6;
      const int v  = v0 + tv;
#pragma unroll
      for (int e0 = 0; e0 < NE; e0 += 4) {
        int e = e0 + te;
        float val = (v < VOCAB) ? w2[(long)e * VOCAB + v] : 0.f;
        tile[tv][e] = __float2bfloat16(val);
      }
      __syncthreads();
#pragma unroll
      for (int it = 0; it < 16; ++it) {
        int f  = it * 256 + threadIdx.x;
        int r  = f >> 6;
        int c2 = f & 63;
        int vv = v0 + r;
        if (vv < VOCAB) {
          ushort2 p;
          p.x = *reinterpret_cast<const unsigned short*>(&tile[r][2 * c2]);
          p.y = *reinterpret_cast<const unsigned short*>(&tile[r][2 * c2 + 1]);
          reinterpret_cast<ushort2*>(w2T + (long)vv * NE)[c2] = p;
        }
      }
      __syncthreads();   // protect tile across reps
    }
  }
}

// ---------------- LSE GEMM (128x128 tiles).  REP-instrumented (idempotent). ----------------
__global__ __launch_bounds__(256) void k_lsegemm(
    const __hip_bfloat16* __restrict__ z1,
    const __hip_bfloat16* __restrict__ w2T,
    float* __restrict__ pmax, float* __restrict__ psum, int reps) {
  __shared__ float sm[2][128];
  __shared__ float ss[2][128];
  const int bid = blockIdx.x;
  const int g = (bid & 7) * (NWG / 8) + (bid >> 3);
  const int chunk = g >> 4;
  const int rowg  = g & 15;
  const int lane = threadIdx.x & 63;
  const int wave = threadIdx.x >> 6;
  const int wm = wave >> 1, wn = wave & 1;
  const int l15 = lane & 15, lhi = lane >> 4;
  const int row0 = rowg * 128 + wm * 64;
  const int col0 = chunk * 128 + wn * 64;

  for (int rep = 0; rep < reps; ++rep) {
    asm volatile("" ::: "memory");
    bf16x8 bz[4][4];
    const __hip_bfloat16* zp = z1 + (row0 + l15) * NE + lhi * 8;
#pragma unroll
    for (int ri = 0; ri < 4; ++ri)
#pragma unroll
      for (int kb = 0; kb < 4; ++kb)
        bz[ri][kb] = *reinterpret_cast<const bf16x8*>(zp + ri * 16 * NE + kb * 32);

    f32x4 acc[4][4];
#pragma unroll
    for (int vi = 0; vi < 4; ++vi)
#pragma unroll
      for (int ri = 0; ri < 4; ++ri)
        acc[vi][ri] = (f32x4){0.f, 0.f, 0.f, 0.f};

#pragma unroll
    for (int vi = 0; vi < 4; ++vi) {
      int col  = col0 + vi * 16 + l15;
      int colc = col < VOCAB ? col : VOCAB - 1;
      const __hip_bfloat16* wp = w2T + colc * NE + lhi * 8;
      bf16x8 aw[4];
#pragma unroll
      for (int kb = 0; kb < 4; ++kb)
        aw[kb] = *reinterpret_cast<const bf16x8*>(wp + kb * 32);
#pragma unroll
      for (int ri = 0; ri < 4; ++ri)
#pragma unroll
        for (int kb = 0; kb < 4; ++kb)
          acc[vi][ri] = __builtin_amdgcn_mfma_f32_16x16x32_bf16(aw[kb], bz[ri][kb], acc[vi][ri], 0, 0, 0);
    }

#pragma unroll
    for (int ri = 0; ri < 4; ++ri) {
      float v[16];
      float m = -INFINITY;
#pragma unroll
      for (int vi = 0; vi < 4; ++vi)
#pragma unroll
        for (int r = 0; r < 4; ++r) {
          int col = col0 + vi * 16 + lhi * 4 + r;
          float x = (col < VOCAB) ? acc[vi][ri][r] : -INFINITY;
          v[vi * 4 + r] = x;
          m = fmaxf(m, x);
        }
      m = fmaxf(m, __shfl_xor(m, 16));
      m = fmaxf(m, __shfl_xor(m, 32));
      float s = 0.f;
#pragma unroll
      for (int t = 0; t < 16; ++t) s += __expf(v[t] - m);
      s += __shfl_xor(s, 16);
      s += __shfl_xor(s, 32);
      if (lhi == 0) {
        int lr = wm * 64 + ri * 16 + l15;
        sm[wn][lr] = m;
        ss[wn][lr] = s;
      }
    }
    __syncthreads();
    if (threadIdx.x < 128) {
      int r = threadIdx.x;
      float m0 = sm[0][r], m1 = sm[1][r];
      float s0 = ss[0][r], s1 = ss[1][r];
      float M = fmaxf(m0, m1);
      float S = s0 * __expf(m0 - M) + s1 * __expf(m1 - M);
      int o = chunk * NB + rowg * 128 + r;
      pmax[o] = M;
      psum[o] = S;
    }
    __syncthreads();   // protect sm/ss across reps
  }
}

// ---------------- two-stage chunk-partial merge -> lse[b] (1x, provably small) ----------------
__global__ void k_lse_part(const float* __restrict__ pmax, const float* __restrict__ psum,
                           float* __restrict__ m2, float* __restrict__ s2) {
  int b  = blockIdx.x * 256 + threadIdx.x;
  int cg = blockIdx.y;
  int c0 = cg * 50, c1 = (c0 + 50 < NCH) ? c0 + 50 : NCH;
  float M = -INFINITY;
  for (int c = c0; c < c1; ++c) M = fmaxf(M, pmax[c * NB + b]);
  float S = 0.f;
  for (int c = c0; c < c1; ++c) S += psum[c * NB + b] * __expf(pmax[c * NB + b] - M);
  m2[cg * NB + b] = M;
  s2[cg * NB + b] = S;
}

__global__ void k_lse_final(const float* __restrict__ m2, const float* __restrict__ s2,
                            float* __restrict__ lse) {
  int b = blockIdx.x * 256 + threadIdx.x;
  float M = -INFINITY;
#pragma unroll
  for (int g = 0; g < 8; ++g) M = fmaxf(M, m2[g * NB + b]);
  float S = 0.f;
#pragma unroll
  for (int g = 0; g < 8; ++g) S += s2[g * NB + b] * __expf(m2[g * NB + b] - M);
  lse[b] = M + __logf(S);
}

// ---------------- OUT GEMM (32x512 tiles).  REP-instrumented (idempotent). ----------------
__global__ __launch_bounds__(256) void k_out(
    const __hip_bfloat16* __restrict__ z1,
    const __hip_bfloat16* __restrict__ w2T,
    const float* __restrict__ lse,
    float* __restrict__ out, int reps) {
  const int bid = blockIdx.x;
  const int g = (bid & 7) * (ONWG / 8) + (bid >> 3);
  const int chunk = g / ORG;
  const int rowg  = g % ORG;
  const int lane = threadIdx.x & 63;
  const int wave = threadIdx.x >> 6;
  const int l15 = lane & 15, lhi = lane >> 4;
  const int row0 = rowg * 32;
  const int col0 = chunk * 512 + wave * 128;

  for (int rep = 0; rep < reps; ++rep) {
    asm volatile("" ::: "memory");
    bf16x8 bz[2][4];
    const __hip_bfloat16* zp = z1 + (row0 + l15) * NE + lhi * 8;
#pragma unroll
    for (int ri = 0; ri < 2; ++ri)
#pragma unroll
      for (int kb = 0; kb < 4; ++kb)
        bz[ri][kb] = *reinterpret_cast<const bf16x8*>(zp + ri * 16 * NE + kb * 32);

    f32x4 acc[8][2];
#pragma unroll
    for (int vi = 0; vi < 8; ++vi)
#pragma unroll
      for (int ri = 0; ri < 2; ++ri)
        acc[vi][ri] = (f32x4){0.f, 0.f, 0.f, 0.f};

#pragma unroll
    for (int vi = 0; vi < 8; ++vi) {
      int col  = col0 + vi * 16 + l15;
      int colc = col < VOCAB ? col : VOCAB - 1;
      const __hip_bfloat16* wp = w2T + colc * NE + lhi * 8;
      bf16x8 aw[4];
#pragma unroll
      for (int kb = 0; kb < 4; ++kb)
        aw[kb] = *reinterpret_cast<const bf16x8*>(wp + kb * 32);
#pragma unroll
      for (int ri = 0; ri < 2; ++ri)
#pragma unroll
        for (int kb = 0; kb < 4; ++kb)
          acc[vi][ri] = __builtin_amdgcn_mfma_f32_16x16x32_bf16(aw[kb], bz[ri][kb], acc[vi][ri], 0, 0, 0);
    }

    float lsev[2] = {lse[row0 + l15], lse[row0 + 16 + l15]};
#pragma unroll
    for (int ri = 0; ri < 2; ++ri) {
      long obase = (long)(row0 + ri * 16 + l15) * VOCAB;
#pragma unroll
      for (int vi = 0; vi < 8; ++vi) {
        int col = col0 + vi * 16 + lhi * 4;
        f32x4 v = acc[vi][ri] - lsev[ri];
        if (col + 3 < VOCAB) {
          *reinterpret_cast<f32x4*>(out + obase + col) = v;
        } else {
#pragma unroll
          for (int r = 0; r < 4; ++r)
            if (col + r < VOCAB) out[obase + col + r] = v[r];
        }
      }
    }
  }
}

extern "C" void kernel_launch(void* const* d_in, const int* in_sizes, int n_in,
                              void* d_out, int out_size, void* d_ws, size_t ws_size,
                              hipStream_t stream) {
  const float* one_hot = (const float*)d_in[0];
  const float* w1      = (const float*)d_in[1];
  const float* w2      = (const float*)d_in[2];
  float* out = (float*)d_out;

  char* ws = (char*)d_ws;
  __hip_bfloat16* z1   = (__hip_bfloat16*)(ws + 8192);   // 512 KB
  __hip_bfloat16* w2T  = (__hip_bfloat16*)(ws + 532480); // 12.87 MB
  float*          pmax = (float*)(ws + 13398272);        // 3.22 MB
  float*          psum = (float*)(ws + 16617728);        // 3.22 MB
  float*          m2   = (float*)(ws + 19837184);        // 64 KB
  float*          s2   = (float*)(ws + 19902720);        // 64 KB
  float*          lse  = (float*)(ws + 19968256);        // 8 KB

  const int REPS = 3;   // diagnostic: phase cost = dur/3; all repped kernels idempotent
  k_prep<<<NFIND + NTR, 256, 0, stream>>>(one_hot, w1, w2, z1, w2T, REPS);
  k_lsegemm<<<NWG, 256, 0, stream>>>(z1, w2T, pmax, psum, REPS);
  k_lse_part<<<dim3(NB / 256, 8), 256, 0, stream>>>(pmax, psum, m2, s2);
  k_lse_final<<<NB / 256, 256, 0, stream>>>(m2, s2, lse);
  k_out<<<ONWG, 256, 0, stream>>>(z1, w2T, lse, out, REPS);
}

// Round 11
// 406.858 us; speedup vs baseline: 2.8483x; 2.4128x over previous
//
#include <hip/hip_runtime.h>
#include <hip/hip_bf16.h>

#define VOCAB 50257
#define NB    2048
#define NE    128
#define NCH   393              // ceil(VOCAB/128)  (LSE pass chunking)
#define NWG   (NCH * (NB/128)) // 6288 = 8 * 786
#define NFIND (NB / 4)         // 512 find blocks
#define NTR   ((VOCAB + 63) / 64) // 786 transpose blocks
#define OCH   99               // ceil(VOCAB/512)  (OUT pass chunking)
#define ORG   (NB / 32)        // 64 row groups
#define ONWG  (OCH * ORG)      // 6336 = 8 * 792
#define OTILES 8               // tiles per persistent k_out block
#define OGRID (ONWG / OTILES)  // 792 blocks, ~3/CU, all co-resident

typedef __bf16 bf16x8 __attribute__((ext_vector_type(8)));
typedef float  f32x4  __attribute__((ext_vector_type(4)));

// ---------------- fused prep: find+gather | transpose (r6-identical) ----------------
__global__ __launch_bounds__(256) void k_prep(const float* __restrict__ oh,
                                              const float* __restrict__ w1,
                                              const float* __restrict__ w2,
                                              __hip_bfloat16* __restrict__ z1,
                                              __hip_bfloat16* __restrict__ w2T) {
  __shared__ __hip_bfloat16 tile[64][130];
  if (blockIdx.x < NFIND) {
    const int w    = (blockIdx.x * 256 + threadIdx.x) >> 6;
    const int lane = threadIdx.x & 63;
    const float* row = oh + (long)w * VOCAB;
    const int a = (4 - (w & 3)) & 3;
    const f32x4* rp = reinterpret_cast<const f32x4*>(row + a);

    int pos = -1;
    f32x4 v[4], nv[4];
#pragma unroll
    for (int j = 0; j < 4; ++j) v[j] = rp[j * 64 + lane];
    bool found = false;
    for (int i = 0; i < 48 && !found; ++i) {
      if (i + 1 < 48) {
#pragma unroll
        for (int j = 0; j < 4; ++j) nv[j] = rp[(i + 1) * 256 + j * 64 + lane];
      }
      bool f = false;
#pragma unroll
      for (int j = 0; j < 4; ++j)
        f |= (v[j][0] != 0.f) | (v[j][1] != 0.f) | (v[j][2] != 0.f) | (v[j][3] != 0.f);
      if (f) {
#pragma unroll
        for (int j = 0; j < 4; ++j)
#pragma unroll
          for (int k = 0; k < 4; ++k)
            if (v[j][k] != 0.f) pos = a + (i * 256 + j * 64 + lane) * 4 + k;
      }
      found = __any(f);
      if (!found) {
#pragma unroll
        for (int j = 0; j < 4; ++j) v[j] = nv[j];
      }
    }
    if (!found) {
      if (lane < a && row[lane] != 0.f) pos = lane;
      for (int e = a + 49152 + lane; e < VOCAB; e += 64)
        if (row[e] != 0.f) pos = e;
    }
#pragma unroll
    for (int off = 1; off < 64; off <<= 1) {
      int o = __shfl_xor(pos, off);
      pos = pos > o ? pos : o;
    }
    if (pos >= 0) {
      float2 wv = *reinterpret_cast<const float2*>(w1 + (long)pos * NE + lane * 2);
      ushort2 p;
      p.x = (ushort)__bfloat16_as_ushort(__float2bfloat16(wv.x));
      p.y = (ushort)__bfloat16_as_ushort(__float2bfloat16(wv.y));
      *reinterpret_cast<ushort2*>(z1 + (long)w * NE + lane * 2) = p;
    }
  } else {
    const int v0 = (blockIdx.x - NFIND) * 64;
    const int tv = threadIdx.x & 63;
    const int te = threadIdx.x >> 6;
    const int v  = v0 + tv;
#pragma unroll
    for (int e0 = 0; e0 < NE; e0 += 4) {
      int e = e0 + te;
      float val = (v < VOCAB) ? w2[(long)e * VOCAB + v] : 0.f;
      tile[tv][e] = __float2bfloat16(val);
    }
    __syncthreads();
#pragma unroll
    for (int it = 0; it < 16; ++it) {
      int f  = it * 256 + threadIdx.x;
      int r  = f >> 6;
      int c2 = f & 63;
      int vv = v0 + r;
      if (vv < VOCAB) {
        ushort2 p;
        p.x = *reinterpret_cast<const unsigned short*>(&tile[r][2 * c2]);
        p.y = *reinterpret_cast<const unsigned short*>(&tile[r][2 * c2 + 1]);
        reinterpret_cast<ushort2*>(w2T + (long)vv * NE)[c2] = p;
      }
    }
  }
}

// ---------------- LSE GEMM (128x128 tiles; r6-identical) ----------------
__global__ __launch_bounds__(256) void k_lsegemm(
    const __hip_bfloat16* __restrict__ z1,
    const __hip_bfloat16* __restrict__ w2T,
    float* __restrict__ pmax, float* __restrict__ psum) {
  __shared__ float sm[2][128];
  __shared__ float ss[2][128];
  const int bid = blockIdx.x;
  const int g = (bid & 7) * (NWG / 8) + (bid >> 3);
  const int chunk = g >> 4;
  const int rowg  = g & 15;
  const int lane = threadIdx.x & 63;
  const int wave = threadIdx.x >> 6;
  const int wm = wave >> 1, wn = wave & 1;
  const int l15 = lane & 15, lhi = lane >> 4;
  const int row0 = rowg * 128 + wm * 64;
  const int col0 = chunk * 128 + wn * 64;

  bf16x8 bz[4][4];
  const __hip_bfloat16* zp = z1 + (row0 + l15) * NE + lhi * 8;
#pragma unroll
  for (int ri = 0; ri < 4; ++ri)
#pragma unroll
    for (int kb = 0; kb < 4; ++kb)
      bz[ri][kb] = *reinterpret_cast<const bf16x8*>(zp + ri * 16 * NE + kb * 32);

  f32x4 acc[4][4];
#pragma unroll
  for (int vi = 0; vi < 4; ++vi)
#pragma unroll
    for (int ri = 0; ri < 4; ++ri)
      acc[vi][ri] = (f32x4){0.f, 0.f, 0.f, 0.f};

#pragma unroll
  for (int vi = 0; vi < 4; ++vi) {
    int col  = col0 + vi * 16 + l15;
    int colc = col < VOCAB ? col : VOCAB - 1;
    const __hip_bfloat16* wp = w2T + colc * NE + lhi * 8;
    bf16x8 aw[4];
#pragma unroll
    for (int kb = 0; kb < 4; ++kb)
      aw[kb] = *reinterpret_cast<const bf16x8*>(wp + kb * 32);
#pragma unroll
    for (int ri = 0; ri < 4; ++ri)
#pragma unroll
      for (int kb = 0; kb < 4; ++kb)
        acc[vi][ri] = __builtin_amdgcn_mfma_f32_16x16x32_bf16(aw[kb], bz[ri][kb], acc[vi][ri], 0, 0, 0);
  }

#pragma unroll
  for (int ri = 0; ri < 4; ++ri) {
    float v[16];
    float m = -INFINITY;
#pragma unroll
    for (int vi = 0; vi < 4; ++vi)
#pragma unroll
      for (int r = 0; r < 4; ++r) {
        int col = col0 + vi * 16 + lhi * 4 + r;
        float x = (col < VOCAB) ? acc[vi][ri][r] : -INFINITY;
        v[vi * 4 + r] = x;
        m = fmaxf(m, x);
      }
    m = fmaxf(m, __shfl_xor(m, 16));
    m = fmaxf(m, __shfl_xor(m, 32));
    float s = 0.f;
#pragma unroll
    for (int t = 0; t < 16; ++t) s += __expf(v[t] - m);
    s += __shfl_xor(s, 16);
    s += __shfl_xor(s, 32);
    if (lhi == 0) {
      int lr = wm * 64 + ri * 16 + l15;
      sm[wn][lr] = m;
      ss[wn][lr] = s;
    }
  }
  __syncthreads();
  if (threadIdx.x < 128) {
    int r = threadIdx.x;
    float m0 = sm[0][r], m1 = sm[1][r];
    float s0 = ss[0][r], s1 = ss[1][r];
    float M = fmaxf(m0, m1);
    float S = s0 * __expf(m0 - M) + s1 * __expf(m1 - M);
    int o = chunk * NB + rowg * 128 + r;
    pmax[o] = M;
    psum[o] = S;
  }
}

// ---------------- two-stage chunk-partial merge -> lse[b] ----------------
__global__ void k_lse_part(const float* __restrict__ pmax, const float* __restrict__ psum,
                           float* __restrict__ m2, float* __restrict__ s2) {
  int b  = blockIdx.x * 256 + threadIdx.x;
  int cg = blockIdx.y;
  int c0 = cg * 50, c1 = (c0 + 50 < NCH) ? c0 + 50 : NCH;
  float M = -INFINITY;
  for (int c = c0; c < c1; ++c) M = fmaxf(M, pmax[c * NB + b]);
  float S = 0.f;
  for (int c = c0; c < c1; ++c) S += psum[c * NB + b] * __expf(pmax[c * NB + b] - M);
  m2[cg * NB + b] = M;
  s2[cg * NB + b] = S;
}

__global__ void k_lse_final(const float* __restrict__ m2, const float* __restrict__ s2,
                            float* __restrict__ lse) {
  int b = blockIdx.x * 256 + threadIdx.x;
  float M = -INFINITY;
#pragma unroll
  for (int g = 0; g < 8; ++g) M = fmaxf(M, m2[g * NB + b]);
  float S = 0.f;
#pragma unroll
  for (int g = 0; g < 8; ++g) S += s2[g * NB + b] * __expf(m2[g * NB + b] - M);
  lse[b] = M + __logf(S);
}

// ---------------- OUT GEMM: persistent blocks, 8 x (32x512) tiles each ----------------
// 792 blocks all co-resident (~3/CU). Stores of tile i stay in flight under
// loads+MFMA of tile i+1 (in-order vmcnt retirement: waiting for the new
// loads doesn't drain the older stores). End-of-kernel drain paid once per
// 512KB instead of once per 64KB.
__global__ __launch_bounds__(256) void k_out(
    const __hip_bfloat16* __restrict__ z1,
    const __hip_bfloat16* __restrict__ w2T,
    const float* __restrict__ lse,
    float* __restrict__ out) {
  const int bid = blockIdx.x;
  const int gbase = (bid & 7) * (ONWG / 8) + (bid >> 3) * OTILES;  // XCD-contiguous
  const int lane = threadIdx.x & 63;
  const int wave = threadIdx.x >> 6;  // col quarter
  const int l15 = lane & 15, lhi = lane >> 4;

  for (int i = 0; i < OTILES; ++i) {
    const int g = gbase + i;
    const int chunk = g / ORG;          // 0..98 (512-col chunk)
    const int rowg  = g % ORG;          // 0..63 (32-row group)
    const int row0 = rowg * 32;
    const int col0 = chunk * 512 + wave * 128;

    bf16x8 bz[2][4];
    const __hip_bfloat16* zp = z1 + (row0 + l15) * NE + lhi * 8;
#pragma unroll
    for (int ri = 0; ri < 2; ++ri)
#pragma unroll
      for (int kb = 0; kb < 4; ++kb)
        bz[ri][kb] = *reinterpret_cast<const bf16x8*>(zp + ri * 16 * NE + kb * 32);

    f32x4 acc[8][2];
#pragma unroll
    for (int vi = 0; vi < 8; ++vi)
#pragma unroll
      for (int ri = 0; ri < 2; ++ri)
        acc[vi][ri] = (f32x4){0.f, 0.f, 0.f, 0.f};

#pragma unroll
    for (int vi = 0; vi < 8; ++vi) {
      int col  = col0 + vi * 16 + l15;
      int colc = col < VOCAB ? col : VOCAB - 1;
      const __hip_bfloat16* wp = w2T + colc * NE + lhi * 8;
      bf16x8 aw[4];
#pragma unroll
      for (int kb = 0; kb < 4; ++kb)
        aw[kb] = *reinterpret_cast<const bf16x8*>(wp + kb * 32);
#pragma unroll
      for (int ri = 0; ri < 2; ++ri)
#pragma unroll
        for (int kb = 0; kb < 4; ++kb)
          acc[vi][ri] = __builtin_amdgcn_mfma_f32_16x16x32_bf16(aw[kb], bz[ri][kb], acc[vi][ri], 0, 0, 0);
    }

    float lsev[2] = {lse[row0 + l15], lse[row0 + 16 + l15]};
#pragma unroll
    for (int ri = 0; ri < 2; ++ri) {
      long obase = (long)(row0 + ri * 16 + l15) * VOCAB;
#pragma unroll
      for (int vi = 0; vi < 8; ++vi) {
        int col = col0 + vi * 16 + lhi * 4;
        f32x4 v = acc[vi][ri] - lsev[ri];
        if (col + 3 < VOCAB) {
          *reinterpret_cast<f32x4*>(out + obase + col) = v;
        } else {
#pragma unroll
          for (int r = 0; r < 4; ++r)
            if (col + r < VOCAB) out[obase + col + r] = v[r];
        }
      }
    }
  }
}

extern "C" void kernel_launch(void* const* d_in, const int* in_sizes, int n_in,
                              void* d_out, int out_size, void* d_ws, size_t ws_size,
                              hipStream_t stream) {
  const float* one_hot = (const float*)d_in[0];
  const float* w1      = (const float*)d_in[1];
  const float* w2      = (const float*)d_in[2];
  float* out = (float*)d_out;

  char* ws = (char*)d_ws;
  __hip_bfloat16* z1   = (__hip_bfloat16*)(ws + 8192);   // 512 KB
  __hip_bfloat16* w2T  = (__hip_bfloat16*)(ws + 532480); // 12.87 MB
  float*          pmax = (float*)(ws + 13398272);        // 3.22 MB
  float*          psum = (float*)(ws + 16617728);        // 3.22 MB
  float*          m2   = (float*)(ws + 19837184);        // 64 KB
  float*          s2   = (float*)(ws + 19902720);        // 64 KB
  float*          lse  = (float*)(ws + 19968256);        // 8 KB

  k_prep<<<NFIND + NTR, 256, 0, stream>>>(one_hot, w1, w2, z1, w2T);
  k_lsegemm<<<NWG, 256, 0, stream>>>(z1, w2T, pmax, psum);
  k_lse_part<<<dim3(NB / 256, 8), 256, 0, stream>>>(pmax, psum, m2, s2);
  k_lse_final<<<NB / 256, 256, 0, stream>>>(m2, s2, lse);
  k_out<<<OGRID, 256, 0, stream>>>(z1, w2T, lse, out);
}